// Round 7
// baseline (722.825 us; speedup 1.0000x reference)
//
#include <hip/hip_runtime.h>
#include <stdint.h>

// out[m,n] = prod_d softplus(min(Zm,Ze)-max(zm,ze)) / softplus(Zm-zm)
//
// R7 = R6 sparsity design, bound pass in plain f32 (R6's fp16 path scalarized:
// 29 us VALU-busy vs 8 predicted, 21% VALUBusy -> latency swamp).
//
//  1) ivr_stats (1 block): Lm = sum_d log2(softplus_nat(Zm-zm)),
//     rcM[m][c] = 1/prod_{8d} log2(1+e^s),
//     Cm[m] = 64*ln(expm1(2^((Lm-43.5)/64)))  [Jensen cut on T]
//  2) ivr_bound (dense f32): T = sum_d [min(Zm,Ze) + min(-zm,-ze)], 4 VALU
//     ops/unit. Jensen (log2∘softplus concave): log2(out) <= 64*log2(sp(T/64))
//     - Lm, so (bound >= -43.5) <=> (T >= Cm). Zero-writes the tile,
//     ballot-compacts survivors. Zeroed => true < 2^-43.5 = 2.5e-14 << thr
//     8.09e-13 (R6 observed zeroed-max 8.66e-15). d-split DH=32 -> 25.5 KB
//     LDS -> 6 blocks/CU; balanced 157x8 grid (2 n-tiles/block co-resident).
//  3) ivr_exact: grid-stride over compacted queue, R2-accurate math.
//  Fallback: self-contained R2 kernel.

#define BM 32
#define BN 64
#define DH 32
#define MST 34   // stride 2 mod 32 -> 2-way (free); 8B-aligned float2
#define NST 68   // stride 4 mod 32; 16B-aligned float4 rows (68*4=272)
#define CUT 43.5f
#define QOFF 9232   // bytes: 16 (count) + 1024 (Cm) + 8192 (rcM)

// ---------------- kernel 1: per-m constants ----------------
__global__ __launch_bounds__(256)
void ivr_stats(const float* __restrict__ men, float* __restrict__ ws, int M) {
    const int tx = threadIdx.x;
    if (tx == 0) *((unsigned*)ws) = 0u;
    float* Cm  = (float*)((char*)ws + 16);
    float* rcM = Cm + 256;
    if (tx >= M) return;
    const float* row = men + (size_t)tx * 128;
    float Lm = 0.f;
    for (int c = 0; c < 8; ++c) {
        float prod = 1.f;
        #pragma unroll
        for (int k = 0; k < 8; ++k) {
            const int d = c * 8 + k;
            const float u = __expf(row[64 + d] - row[d]);
            const float w = 1.f + u;
            float l2 = __log2f(w);
            if (u < 0.5f) l2 += (u - (w - 1.f)) * 1.44269504f;  // log1p fixup
            prod *= l2;
            Lm += __log2f(l2 * 0.69314718f);   // log2(natural softplus)
        }
        rcM[tx * 8 + c] = 1.f / prod;
    }
    const float V = exp2f((Lm - CUT) * (1.f / 64.f));
    Cm[tx] = 64.f * __logf(expm1f(V));
}

// ---------------- kernel 2: dense f32 bound + compaction ----------------
__global__ __launch_bounds__(256, 6)
void ivr_bound(const float* __restrict__ men, const float* __restrict__ en,
               float* __restrict__ out, float* __restrict__ ws,
               int M, int N, int ntl, int jst, unsigned qcap) {
    __shared__ __align__(16) float sMZ [DH][MST];  // Zm   [d][m]  4.25 KB
    __shared__ __align__(16) float sMnz[DH][MST];  // -zm
    __shared__ __align__(16) float sEZ [DH][NST];  // Ze   [d][n]  8.5 KB
    __shared__ __align__(16) float sEnz[DH][NST];  // -ze          -> 25.5 KB

    const int tx = threadIdx.x;
    const int mt = blockIdx.y, j = blockIdx.x;
    const int m0 = mt * BM;
    const int ntiles = (j + jst < ntl) ? 2 : 1;

    const float* Cm = (const float*)((const char*)ws + 16);
    unsigned* qcount = (unsigned*)ws;
    unsigned* queue  = (unsigned*)((char*)ws + QOFF);

    const int ni = (tx & 15) * 4;    // 16 n-groups of 4
    const int mi = (tx >> 4) * 2;    // 16 m-groups of 2
    const int lane = tx & 63;

    for (int t = 0; t < ntiles; ++t) {
        const int n0 = (j + t * jst) * BN;

        float acc[2][4];
        #pragma unroll
        for (int i = 0; i < 2; ++i)
            #pragma unroll
            for (int jj = 0; jj < 4; ++jj) acc[i][jj] = 0.f;

        #pragma unroll 1
        for (int h = 0; h < 2; ++h) {
            const int dofs = h * DH;
            __syncthreads();   // prior reads done before overwrite

            // ---- men staging: threads 0..127 -> (m = tx&31, 8 d's) ----
            if (tx < 128) {
                const int m = tx & 31;
                const int dg = tx >> 5;                // 0..3
                int mm = m0 + m; if (mm >= M) mm = M - 1;
                const float* row = men + (size_t)mm * 128 + dofs + dg * 8;
                const float4 za = *(const float4*)(row);
                const float4 zb = *(const float4*)(row + 4);
                const float4 Za = *(const float4*)(row + 64);
                const float4 Zb = *(const float4*)(row + 68);
                const float zA[8] = {za.x, za.y, za.z, za.w, zb.x, zb.y, zb.z, zb.w};
                const float ZA[8] = {Za.x, Za.y, Za.z, Za.w, Zb.x, Zb.y, Zb.z, Zb.w};
                #pragma unroll
                for (int k = 0; k < 8; ++k) {
                    const int dl = dg * 8 + k;
                    sMZ [dl][m] = ZA[k];               // banks (2d+m)%32: 2-way free
                    sMnz[dl][m] = -zA[k];
                }
            }
            // ---- entity staging: all threads, float4 coalesced ----
            #pragma unroll
            for (int it = 0; it < 2; ++it) {
                const int q   = tx + it * 256;         // 512 quads = 64n x 8 d-quads
                const int dl4 = (q & 7) * 4;
                const int n   = q >> 3;
                int nn = n0 + n; if (nn >= N) nn = N - 1;
                const float* erow = en + (size_t)nn * 128 + dofs + dl4;
                const float4 z4 = *(const float4*)(erow);
                const float4 Z4 = *(const float4*)(erow + 64);
                sEZ [dl4 + 0][n] = Z4.x;  sEZ [dl4 + 1][n] = Z4.y;
                sEZ [dl4 + 2][n] = Z4.z;  sEZ [dl4 + 3][n] = Z4.w;
                sEnz[dl4 + 0][n] = -z4.x; sEnz[dl4 + 1][n] = -z4.y;
                sEnz[dl4 + 2][n] = -z4.z; sEnz[dl4 + 3][n] = -z4.w;
            }
            __syncthreads();

            // ---- accumulate T over this phase's 32 dims ----
            #pragma unroll 1
            for (int c = 0; c < 4; ++c) {
                #pragma unroll
                for (int k = 0; k < 8; ++k) {
                    const int dl = c * 8 + k;
                    const float2 mZ  = *(const float2*)&sMZ [dl][mi];
                    const float2 mnz = *(const float2*)&sMnz[dl][mi];
                    const float4 eZ  = *(const float4*)&sEZ [dl][ni];
                    const float4 enz = *(const float4*)&sEnz[dl][ni];
                    const float mZA[2]  = {mZ.x, mZ.y};
                    const float mnzA[2] = {mnz.x, mnz.y};
                    const float eZA[4]  = {eZ.x, eZ.y, eZ.z, eZ.w};
                    const float enzA[4] = {enz.x, enz.y, enz.z, enz.w};
                    #pragma unroll
                    for (int i = 0; i < 2; ++i) {
                        #pragma unroll
                        for (int jj = 0; jj < 4; ++jj) {
                            acc[i][jj] += fminf(mZA[i], eZA[jj]) +
                                          fminf(mnzA[i], enzA[jj]);
                        }
                    }
                }
            }
        }

        // ---- cut test, zero-store, ballot-compact survivors ----
        const float cm0 = Cm[m0 + mi], cm1 = Cm[m0 + mi + 1];
        #pragma unroll
        for (int i = 0; i < 2; ++i) {
            const int m = m0 + mi + i;
            const int n = n0 + ni;
            if (m < M) {
                if (n + 4 <= N)
                    *(float4*)&out[(size_t)m * N + n] = make_float4(0.f, 0.f, 0.f, 0.f);
                else
                    for (int jj = 0; jj < 4; ++jj)
                        if (n + jj < N) out[(size_t)m * N + n + jj] = 0.f;
            }
        }
        #pragma unroll
        for (int i = 0; i < 2; ++i) {
            const int m = m0 + mi + i;
            const float cmv = i ? cm1 : cm0;
            #pragma unroll
            for (int jj = 0; jj < 4; ++jj) {
                const int n = n0 + ni + jj;
                const bool flag = (acc[i][jj] >= cmv - 0.01f) && (n < N) && (m < M);
                const unsigned long long mask = __ballot(flag);
                if (mask) {
                    const int lead = (int)__ffsll(mask) - 1;
                    unsigned base = 0;
                    if (lane == lead) base = atomicAdd(qcount, (unsigned)__popcll(mask));
                    base = (unsigned)__shfl((int)base, lead, 64);
                    if (flag) {
                        const unsigned off =
                            (unsigned)__popcll(mask & ((1ull << lane) - 1ull));
                        const unsigned idx = base + off;
                        if (idx < qcap) queue[idx] = ((unsigned)m << 16) | (unsigned)n;
                    }
                }
            }
        }
    }
}

// ---------------- kernel 3: exact path on compacted survivors ----------------
__global__ __launch_bounds__(256)
void ivr_exact(const float* __restrict__ men, const float* __restrict__ en,
               float* __restrict__ out, const float* __restrict__ ws,
               int N, unsigned qcap) {
    const unsigned nq0 = *((const unsigned*)ws);
    const unsigned nq = nq0 < qcap ? nq0 : qcap;
    const float* rcM = (const float*)((const char*)ws + 16) + 256;
    const unsigned* queue = (const unsigned*)((const char*)ws + QOFF);
    for (unsigned idx = blockIdx.x * 256 + threadIdx.x; idx < nq;
         idx += gridDim.x * 256) {
        const unsigned id = queue[idx];
        const int m = (int)(id >> 16), n = (int)(id & 0xFFFFu);
        const float* mr = men + (size_t)m * 128;
        const float* er = en + (size_t)n * 128;
        float p = 1.f;
        #pragma unroll 1
        for (int c = 0; c < 8; ++c) {
            float q = 1.f;
            #pragma unroll
            for (int h = 0; h < 2; ++h) {
                const int d0 = c * 8 + h * 4;
                const float4 zm4 = *(const float4*)(mr + d0);
                const float4 Zm4 = *(const float4*)(mr + 64 + d0);
                const float4 ze4 = *(const float4*)(er + d0);
                const float4 Ze4 = *(const float4*)(er + 64 + d0);
                const float zmA[4] = {zm4.x, zm4.y, zm4.z, zm4.w};
                const float ZmA[4] = {Zm4.x, Zm4.y, Zm4.z, Zm4.w};
                const float zeA[4] = {ze4.x, ze4.y, ze4.z, ze4.w};
                const float ZeA[4] = {Ze4.x, Ze4.y, Ze4.z, Ze4.w};
                #pragma unroll
                for (int e = 0; e < 4; ++e) {
                    const float t = fminf(ZmA[e], ZeA[e]) - fmaxf(zmA[e], zeA[e]);
                    const float u = __expf(t);
                    q *= __log2f(1.f + u);
                }
            }
            p *= q * rcM[m * 8 + c];
        }
        out[(size_t)m * N + n] = p;
    }
}

// ---------------- fallback (R2 kernel, self-contained) ----------------
#define FB_MST 34
#define FB_NST 68
__global__ __launch_bounds__(256, 3)
void ivr_fb(const float* __restrict__ men, const float* __restrict__ en,
            float* __restrict__ out, int M, int N) {
    __shared__ __align__(16) float sEm[64][FB_MST];
    __shared__ __align__(16) float sIm[64][FB_MST];
    __shared__ __align__(16) float sEe[64][FB_NST];
    __shared__ __align__(16) float sIe[64][FB_NST];
    __shared__ float sRc[8][FB_MST];
    const int tx = threadIdx.x;
    const int m0 = blockIdx.y * BM;
    const int n0 = blockIdx.x * BN;
    {
        const int m = tx >> 3, c = tx & 7;
        int mm = m0 + m; if (mm >= M) mm = M - 1;
        const float* row = men + (size_t)mm * 128;
        float prod = 1.f;
        #pragma unroll
        for (int k = 0; k < 8; ++k) {
            const int d = c * 8 + k;
            const float Em = __expf(row[64 + d]);
            const float Im = __expf(-row[d]);
            sEm[d][m] = Em; sIm[d][m] = Im;
            prod *= __log2f(fmaf(Em, Im, 1.f));
        }
        sRc[c][m] = 1.f / prod;
    }
    for (int i = tx; i < BN * 64; i += 256) {
        const int d = i & 63, n = i >> 6;
        int nn = n0 + n; if (nn >= N) nn = N - 1;
        sEe[d][n] = __expf(en[(size_t)nn * 128 + 64 + d]);
        sIe[d][n] = __expf(-en[(size_t)nn * 128 + d]);
    }
    __syncthreads();
    const int ni = (tx & 15) * 4, mi = (tx >> 4) * 2;
    float p[2][4];
    #pragma unroll
    for (int i = 0; i < 2; ++i)
        #pragma unroll
        for (int jj = 0; jj < 4; ++jj) p[i][jj] = 1.f;
    #pragma unroll 1
    for (int c = 0; c < 8; ++c) {
        #pragma unroll
        for (int k = 0; k < 8; ++k) {
            const int d = c * 8 + k;
            const float2 Em2 = *(const float2*)&sEm[d][mi];
            const float2 Im2 = *(const float2*)&sIm[d][mi];
            const float2 Ee0 = *(const float2*)&sEe[d][ni];
            const float2 Ee1 = *(const float2*)&sEe[d][ni + 2];
            const float2 Ie0 = *(const float2*)&sIe[d][ni];
            const float2 Ie1 = *(const float2*)&sIe[d][ni + 2];
            const float EmA[2] = {Em2.x, Em2.y}, ImA[2] = {Im2.x, Im2.y};
            const float EeA[4] = {Ee0.x, Ee0.y, Ee1.x, Ee1.y};
            const float IeA[4] = {Ie0.x, Ie0.y, Ie1.x, Ie1.y};
            #pragma unroll
            for (int i = 0; i < 2; ++i)
                #pragma unroll
                for (int jj = 0; jj < 4; ++jj) {
                    const float ww = fmaf(fminf(EmA[i], EeA[jj]),
                                          fminf(ImA[i], IeA[jj]), 1.f);
                    p[i][jj] *= __log2f(ww);
                }
        }
        const float2 rc = *(const float2*)&sRc[c][mi];
        #pragma unroll
        for (int jj = 0; jj < 4; ++jj) { p[0][jj] *= rc.x; p[1][jj] *= rc.y; }
    }
    #pragma unroll
    for (int i = 0; i < 2; ++i) {
        const int m = m0 + mi + i;
        if (m >= M) continue;
        const int n = n0 + ni;
        if (n + 4 <= N) *(float4*)&out[(size_t)m * N + n] =
            make_float4(p[i][0], p[i][1], p[i][2], p[i][3]);
        else for (int jj = 0; jj < 4; ++jj)
            if (n + jj < N) out[(size_t)m * N + n + jj] = p[i][jj];
    }
}

extern "C" void kernel_launch(void* const* d_in, const int* in_sizes, int n_in,
                              void* d_out, int out_size, void* d_ws, size_t ws_size,
                              hipStream_t stream) {
    const float* men = (const float*)d_in[0];
    const float* en  = (const float*)d_in[1];
    float* out = (float*)d_out;
    const int M = in_sizes[0] / 128;          // 256
    const int N = in_sizes[1] / 128;          // 20000
    const int ntl = (N + BN - 1) / BN;        // 313
    const int mtl = (M + BM - 1) / BM;        // 8
    const int jst = (ntl + 1) / 2;            // 157
    if (M <= 256 && N < 65536 && ws_size >= (size_t)(QOFF + (1u << 20))) {
        const unsigned qcap = (unsigned)((ws_size - QOFF) / 4);
        ivr_stats<<<1, 256, 0, stream>>>(men, (float*)d_ws, M);
        ivr_bound<<<dim3(jst, mtl), 256, 0, stream>>>(men, en, out, (float*)d_ws,
                                                      M, N, ntl, jst, qcap);
        ivr_exact<<<256, 256, 0, stream>>>(men, en, out, (const float*)d_ws,
                                           N, qcap);
    } else {
        ivr_fb<<<dim3(ntl, mtl), 256, 0, stream>>>(men, en, out, M, N);
    }
}